// Round 3
// baseline (1600.369 us; speedup 1.0000x reference)
//
#include <hip/hip_runtime.h>
#include <math.h>
#include <stdint.h>

// out_i = clamp(out_{i-1}; a_i, a_i+1), a_i = x_i * k.  Clamps compose ->
// associative scan. Single-pass decoupled lookback:
//  - atomic ticket => block ids in scheduling order (no dispatch-order assumption)
//  - each block publishes its aggregate clamp (lo,hi) BEFORE lookback
//  - lookback composes predecessor aggregates backward; early-exits as soon as
//    the composed function is constant (lo==hi) -- with ~N(0,1) data this
//    happens after ~1 hop; grounded at state[0] if it walks to block 0.
//  - published inclusive-prefix values are a fast path only, never required
//    for termination => deadlock-free.
// x is read once, out written once: ~67 MB total HBM traffic.

#define TPB 256
#define SEGS 4
#define ELEMS (TPB * SEGS * 4)   // 4096 floats per block

__device__ __forceinline__ float clampf(float x, float lo, float hi) {
    return fminf(fmaxf(x, lo), hi);
}

// 64-bit word = (flag<<32) | float_bits  -> single atomic publish/poll
__device__ __forceinline__ void publish(uint64_t* p, float val) {
    uint64_t w = (1ull << 32) | (uint64_t)__float_as_uint(val);
    __hip_atomic_store(p, w, __ATOMIC_RELEASE, __HIP_MEMORY_SCOPE_AGENT);
}
__device__ __forceinline__ bool poll(uint64_t* p, float* val) {
    uint64_t w = __hip_atomic_load(p, __ATOMIC_ACQUIRE, __HIP_MEMORY_SCOPE_AGENT);
    if ((w >> 32) == 0) return false;
    *val = __uint_as_float((uint32_t)w);
    return true;
}

__global__ __launch_bounds__(TPB) void phi_scan(
    const float4* __restrict__ x4,
    const float* __restrict__ kern,
    const float* __restrict__ state,
    float* __restrict__ out,          // T outputs + 1 new_state
    uint32_t* __restrict__ counter,
    uint64_t* __restrict__ aggLo,
    uint64_t* __restrict__ aggHi,
    uint64_t* __restrict__ pref,
    int nblocks)
{
    __shared__ int s_ticket;
    __shared__ float wtlo[SEGS][TPB / 64], wthi[SEGS][TPB / 64];
    __shared__ float s_vb;

    const int t = threadIdx.x, lane = t & 63, w = t >> 6;
    if (t == 0) s_ticket = (int)atomicAdd(counter, 1u);
    __syncthreads();
    const int b = s_ticket;

    const float k = kern[0];
    const size_t base4 = (size_t)b * (TPB * SEGS);   // float4 units

    float a[SEGS][4];
    float eslo[SEGS], eshi[SEGS];   // thread-exclusive function within segment

    // ---- local + wave scan per segment (coalesced loads: lane i -> float4 i)
#pragma unroll
    for (int s = 0; s < SEGS; ++s) {
        float4 v = x4[base4 + (size_t)s * TPB + t];
        a[s][0] = v.x * k; a[s][1] = v.y * k; a[s][2] = v.z * k; a[s][3] = v.w * k;

        float lo = a[s][0], hi = a[s][0] + 1.0f;
#pragma unroll
        for (int c = 1; c < 4; ++c) {
            lo = clampf(lo, a[s][c], a[s][c] + 1.0f);
            hi = clampf(hi, a[s][c], a[s][c] + 1.0f);
        }
        // wave inclusive scan (prefix FIRST, self SECOND)
#pragma unroll
        for (int off = 1; off < 64; off <<= 1) {
            float plo = __shfl_up(lo, off);
            float phi_ = __shfl_up(hi, off);
            if (lane >= off) {
                float nlo = clampf(plo, lo, hi);
                float nhi = clampf(phi_, lo, hi);
                lo = nlo; hi = nhi;
            }
        }
        float elo = __shfl_up(lo, 1), ehi = __shfl_up(hi, 1);
        if (lane == 0) { elo = -INFINITY; ehi = INFINITY; }
        eslo[s] = elo; eshi[s] = ehi;
        if (lane == 63) { wtlo[s][w] = lo; wthi[s][w] = hi; }
    }
    __syncthreads();

    // ---- compose wave totals: segment totals + full thread-exclusive
    float Slo[SEGS], Shi[SEGS];
#pragma unroll
    for (int s = 0; s < SEGS; ++s) {
        float welo = -INFINITY, wehi = INFINITY;     // earlier waves' total
        for (int i = 0; i < w; ++i) {
            welo = clampf(welo, wtlo[s][i], wthi[s][i]);
            wehi = clampf(wehi, wtlo[s][i], wthi[s][i]);
        }
        float llo = eslo[s], lhi = eshi[s];
        eslo[s] = clampf(welo, llo, lhi);            // compose(Wexc, Lexc)
        eshi[s] = clampf(wehi, llo, lhi);

        float stl = -INFINITY, sth = INFINITY;       // segment total
#pragma unroll
        for (int i = 0; i < TPB / 64; ++i) {
            stl = clampf(stl, wtlo[s][i], wthi[s][i]);
            sth = clampf(sth, wtlo[s][i], wthi[s][i]);
        }
        Slo[s] = stl; Shi[s] = sth;
    }

    // ---- publish aggregate, lookback (thread 0)
    if (t == 0) {
        float Alo = -INFINITY, Ahi = INFINITY;
#pragma unroll
        for (int s = 0; s < SEGS; ++s) {
            Alo = clampf(Alo, Slo[s], Shi[s]);
            Ahi = clampf(Ahi, Slo[s], Shi[s]);
        }
        publish(&aggLo[b], Alo);
        publish(&aggHi[b], Ahi);

        float vb;
        if (b == 0) {
            vb = state[0];
        } else {
            float Flo = -INFINITY, Fhi = INFINITY;   // blocks (j+1 .. b-1)
            int j = b - 1;
            for (;;) {
                if (Flo == Fhi) { vb = Flo; break; } // constant: done
                float pv;
                if (poll(&pref[j], &pv)) { vb = clampf(pv, Flo, Fhi); break; }
                float alo, ahi;
                if (poll(&aggLo[j], &alo) && poll(&aggHi[j], &ahi)) {
                    float nlo = clampf(alo, Flo, Fhi);   // prepend A_j
                    float nhi = clampf(ahi, Flo, Fhi);
                    Flo = nlo; Fhi = nhi;
                    if (--j < 0) { vb = clampf(state[0], Flo, Fhi); break; }
                } else {
                    __builtin_amdgcn_s_sleep(1);
                }
            }
        }
        float Pb = clampf(vb, Alo, Ahi);
        publish(&pref[b], Pb);
        if (b == nblocks - 1) out[(size_t)nblocks * ELEMS] = Pb;  // new_state
        s_vb = vb;
    }
    __syncthreads();

    // ---- apply: chain segment entry values, emit outputs (coalesced stores)
    float4* out4 = (float4*)out;
    float p = s_vb;
#pragma unroll
    for (int s = 0; s < SEGS; ++s) {
        float wv = clampf(p, eslo[s], eshi[s]);      // thread's entry value
        float4 r;
        wv = clampf(wv, a[s][0], a[s][0] + 1.0f); r.x = wv;
        wv = clampf(wv, a[s][1], a[s][1] + 1.0f); r.y = wv;
        wv = clampf(wv, a[s][2], a[s][2] + 1.0f); r.z = wv;
        wv = clampf(wv, a[s][3], a[s][3] + 1.0f); r.w = wv;
        out4[base4 + (size_t)s * TPB + t] = r;
        p = clampf(p, Slo[s], Shi[s]);               // advance past segment
    }
}

extern "C" void kernel_launch(void* const* d_in, const int* in_sizes, int n_in,
                              void* d_out, int out_size, void* d_ws, size_t ws_size,
                              hipStream_t stream) {
    const float* x     = (const float*)d_in[0];   // [1,T]
    const float* state = (const float*)d_in[1];   // [1,1]
    const float* kern  = (const float*)d_in[2];   // [1,1]
    float* out = (float*)d_out;                   // T outputs + 1 new_state

    const size_t T = (size_t)in_sizes[0];
    const int nblocks = (int)(T / ELEMS);         // 2048 for T=2^23

    uint32_t* counter = (uint32_t*)d_ws;
    uint64_t* aggLo = (uint64_t*)((char*)d_ws + 16);
    uint64_t* aggHi = aggLo + nblocks;
    uint64_t* pref  = aggHi + nblocks;
    const size_t ctl_bytes = 16 + 3 * (size_t)nblocks * sizeof(uint64_t);

    hipMemsetAsync(d_ws, 0, ctl_bytes, stream);   // flags=0 (ws is 0xAA-poisoned)
    phi_scan<<<nblocks, TPB, 0, stream>>>((const float4*)x, kern, state, out,
                                          counter, aggLo, aggHi, pref, nblocks);
}

// Round 5
// 101.666 us; speedup vs baseline: 15.7414x; 15.7414x over previous
//
#include <hip/hip_runtime.h>
#include <math.h>

// out_i = clamp(out_{i-1}; a_i, a_i+1), a_i = x_i * k.  Clamp functions
// p -> min(max(p,lo),hi) compose associatively -> parallel scan.
//
// History: R3 decoupled-lookback serialized (data-dependent termination);
// R4 cooperative grid.sync launch silently failed. This round: same
// deterministic algorithm as R4, split at the grid.sync into TWO plain
// kernels. K2 redundantly composes its exclusive prefix over all block
// aggregates (8KB, L2-hot) -- log-depth, no spinning, no assumptions.

#define TPB 256
#define SEGS 8
#define WAVES (TPB / 64)
#define ELEMS (TPB * SEGS * 4)   // 8192 floats per block -> 1024 blocks @ T=2^23

__device__ __forceinline__ float clampf(float x, float lo, float hi) {
    return fminf(fmaxf(x, lo), hi);
}

// ---------------- K1: per-block composed clamp aggregate ----------------
__global__ __launch_bounds__(TPB) void k_agg(const float4* __restrict__ x4,
                                             const float* __restrict__ kern,
                                             float2* __restrict__ agg) {
    __shared__ float wtlo[SEGS][WAVES], wthi[SEGS][WAVES];
    const int t = threadIdx.x, lane = t & 63, w = t >> 6;
    const int b = blockIdx.x;
    const float k = kern[0];
    const size_t base4 = (size_t)b * (TPB * SEGS);

#pragma unroll
    for (int s = 0; s < SEGS; ++s) {
        float4 v = x4[base4 + (size_t)s * TPB + t];   // coalesced
        float a0 = v.x * k, a1 = v.y * k, a2 = v.z * k, a3 = v.w * k;
        float lo = a0, hi = a0 + 1.0f;
        lo = clampf(lo, a1, a1 + 1.0f); hi = clampf(hi, a1, a1 + 1.0f);
        lo = clampf(lo, a2, a2 + 1.0f); hi = clampf(hi, a2, a2 + 1.0f);
        lo = clampf(lo, a3, a3 + 1.0f); hi = clampf(hi, a3, a3 + 1.0f);
        // ordered wave reduce: self (earlier) FIRST, lane+off (later) SECOND.
        // OOB shfl returns self; self-compose of a clamp pair is identity.
#pragma unroll
        for (int off = 1; off < 64; off <<= 1) {
            float plo = __shfl_down(lo, off);
            float phi_ = __shfl_down(hi, off);
            float nlo = clampf(lo, plo, phi_);
            float nhi = clampf(hi, plo, phi_);
            lo = nlo; hi = nhi;
        }
        if (lane == 0) { wtlo[s][w] = lo; wthi[s][w] = hi; }
    }
    __syncthreads();
    if (t == 0) {
        float Alo = -INFINITY, Ahi = INFINITY;
#pragma unroll
        for (int s = 0; s < SEGS; ++s)
#pragma unroll
            for (int i = 0; i < WAVES; ++i) {
                Alo = clampf(Alo, wtlo[s][i], wthi[s][i]);
                Ahi = clampf(Ahi, wtlo[s][i], wthi[s][i]);
            }
        agg[b] = make_float2(Alo, Ahi);
    }
}

// ------- K2: entry value from agg prefix, local scans, apply + write -------
__global__ __launch_bounds__(TPB) void k_apply(
    const float4* __restrict__ x4,
    const float* __restrict__ kern,
    const float* __restrict__ state,
    const float2* __restrict__ agg,
    float* __restrict__ out,          // T outputs + 1 new_state
    int nblocks)
{
    __shared__ float wtlo[SEGS][WAVES], wthi[SEGS][WAVES];
    __shared__ float rlo[WAVES], rhi[WAVES];
    __shared__ float s_vb;

    const int t = threadIdx.x, lane = t & 63, w = t >> 6;
    const int b = blockIdx.x;
    const float k = kern[0];
    const size_t base4 = (size_t)b * (TPB * SEGS);

    float eslo[SEGS], eshi[SEGS];   // thread-exclusive within segment
    float Slo[SEGS], Shi[SEGS];     // segment totals

    // ---- block-local scans (structure validated in R3: absmax 0.0) ----
#pragma unroll
    for (int s = 0; s < SEGS; ++s) {
        float4 v = x4[base4 + (size_t)s * TPB + t];   // coalesced
        float a0 = v.x * k, a1 = v.y * k, a2 = v.z * k, a3 = v.w * k;
        float lo = a0, hi = a0 + 1.0f;
        lo = clampf(lo, a1, a1 + 1.0f); hi = clampf(hi, a1, a1 + 1.0f);
        lo = clampf(lo, a2, a2 + 1.0f); hi = clampf(hi, a2, a2 + 1.0f);
        lo = clampf(lo, a3, a3 + 1.0f); hi = clampf(hi, a3, a3 + 1.0f);
        // wave inclusive scan (prefix FIRST, self SECOND)
#pragma unroll
        for (int off = 1; off < 64; off <<= 1) {
            float plo = __shfl_up(lo, off);
            float phi_ = __shfl_up(hi, off);
            if (lane >= off) {
                float nlo = clampf(plo, lo, hi);
                float nhi = clampf(phi_, lo, hi);
                lo = nlo; hi = nhi;
            }
        }
        float elo = __shfl_up(lo, 1), ehi = __shfl_up(hi, 1);
        if (lane == 0) { elo = -INFINITY; ehi = INFINITY; }
        eslo[s] = elo; eshi[s] = ehi;
        if (lane == 63) { wtlo[s][w] = lo; wthi[s][w] = hi; }
    }
    __syncthreads();

#pragma unroll
    for (int s = 0; s < SEGS; ++s) {
        float welo = -INFINITY, wehi = INFINITY;      // earlier waves' totals
        for (int i = 0; i < w; ++i) {
            welo = clampf(welo, wtlo[s][i], wthi[s][i]);
            wehi = clampf(wehi, wtlo[s][i], wthi[s][i]);
        }
        float llo = eslo[s], lhi = eshi[s];
        eslo[s] = clampf(welo, llo, lhi);             // compose(waves-before, lanes-before)
        eshi[s] = clampf(wehi, llo, lhi);
        float stl = -INFINITY, sth = INFINITY;        // segment total
#pragma unroll
        for (int i = 0; i < WAVES; ++i) {
            stl = clampf(stl, wtlo[s][i], wthi[s][i]);
            sth = clampf(sth, wtlo[s][i], wthi[s][i]);
        }
        Slo[s] = stl; Shi[s] = sth;
    }

    // ---- exclusive prefix over agg[0..b-1] (block-ordered log reduce) ----
    {
        const int per = nblocks / TPB;   // 4
        float lo = -INFINITY, hi = INFINITY;
        for (int c = 0; c < per; ++c) {
            int j = t * per + c;
            if (j < b) {
                float2 ag = agg[j];
                lo = clampf(lo, ag.x, ag.y);
                hi = clampf(hi, ag.x, ag.y);
            }
        }
#pragma unroll
        for (int off = 1; off < 64; off <<= 1) {
            float plo = __shfl_down(lo, off);
            float phi_ = __shfl_down(hi, off);
            float nlo = clampf(lo, plo, phi_);
            float nhi = clampf(hi, plo, phi_);
            lo = nlo; hi = nhi;
        }
        if (lane == 0) { rlo[w] = lo; rhi[w] = hi; }
        __syncthreads();
        if (t == 0) {
            float Plo = rlo[0], Phi = rhi[0];
#pragma unroll
            for (int i = 1; i < WAVES; ++i) {
                Plo = clampf(Plo, rlo[i], rhi[i]);
                Phi = clampf(Phi, rlo[i], rhi[i]);
            }
            s_vb = clampf(state[0], Plo, Phi);   // block entry value
        }
        __syncthreads();
    }

    // ---- apply + write (coalesced) ----
    float p = s_vb;
    float4* out4 = (float4*)out;
#pragma unroll
    for (int s = 0; s < SEGS; ++s) {
        float wv = clampf(p, eslo[s], eshi[s]);       // thread entry in segment
        float4 v = x4[base4 + (size_t)s * TPB + t];   // reload (L2/L3-hot)
        float a0 = v.x * k, a1 = v.y * k, a2 = v.z * k, a3 = v.w * k;
        float4 r;
        wv = clampf(wv, a0, a0 + 1.0f); r.x = wv;
        wv = clampf(wv, a1, a1 + 1.0f); r.y = wv;
        wv = clampf(wv, a2, a2 + 1.0f); r.z = wv;
        wv = clampf(wv, a3, a3 + 1.0f); r.w = wv;
        out4[base4 + (size_t)s * TPB + t] = r;
        p = clampf(p, Slo[s], Shi[s]);                // advance past segment
    }

    if (b == nblocks - 1 && t == 0) {
        float q = s_vb;
#pragma unroll
        for (int s = 0; s < SEGS; ++s) q = clampf(q, Slo[s], Shi[s]);
        out[(size_t)nblocks * ELEMS] = q;             // new_state = last output
    }
}

extern "C" void kernel_launch(void* const* d_in, const int* in_sizes, int n_in,
                              void* d_out, int out_size, void* d_ws, size_t ws_size,
                              hipStream_t stream) {
    const float4* x4   = (const float4*)d_in[0];   // [1,T]
    const float* state = (const float*)d_in[1];    // [1,1]
    const float* kern  = (const float*)d_in[2];    // [1,1]
    float* out = (float*)d_out;                    // T outputs + 1 new_state

    const size_t T = (size_t)in_sizes[0];
    const int nblocks = (int)(T / ELEMS);          // 1024 for T=2^23
    float2* agg = (float2*)d_ws;                   // fully written by K1 before K2 reads

    k_agg<<<nblocks, TPB, 0, stream>>>(x4, kern, agg);
    k_apply<<<nblocks, TPB, 0, stream>>>(x4, kern, state, agg, out, nblocks);
}